// Round 6
// baseline (241.115 us; speedup 1.0000x reference)
//
#include <hip/hip_runtime.h>

#define B_DIM 4
#define L_DIM 4096
#define H_DIM 1024
#define U_DIM 1024
#define M_DIM (B_DIM * L_DIM)   // 16384
#define LC 64                    // scan chunk length
#define NCH (L_DIM / LC)         // 64 chunks per sequence

using f32x4  = __attribute__((ext_vector_type(4))) float;
using bf16x8 = __attribute__((ext_vector_type(8))) __bf16;
using us8    = __attribute__((ext_vector_type(8))) unsigned short;
using u32x2  = __attribute__((ext_vector_type(2))) unsigned int;

__device__ inline unsigned short f32_to_bf16(float f) {
  unsigned int u = __float_as_uint(f);
  u += 0x7FFF + ((u >> 16) & 1);   // round-to-nearest-even
  return (unsigned short)(u >> 16);
}
__device__ inline float bf16_to_f32(unsigned short v) {
  return __uint_as_float((unsigned int)v << 16);
}

__device__ inline void async_load16(const void* g, void* l) {
  // gfx950 global->LDS direct, 16B/lane; LDS dest = wave-uniform base + lane*16.
  __builtin_amdgcn_global_load_lds(
      (const __attribute__((address_space(1))) void*)g,
      (__attribute__((address_space(3))) void*)l, 16, 0, 0);
}

// ---------------- fused fp32 -> bf16 convert: inputs, Wi, Wo ----------------
#define IN_ELEMS  (M_DIM * H_DIM)          // 16777216
#define WI_ELEMS  (U_DIM * H_DIM)          // 1048576
#define WO_ELEMS  (H_DIM * U_DIM)          // 1048576
#define CVT_TOTAL (IN_ELEMS + WI_ELEMS + WO_ELEMS)

__global__ __launch_bounds__(256) void cvt_all(
    const float* __restrict__ inp, const float* __restrict__ wi,
    const float* __restrict__ wo,
    unsigned short* __restrict__ inp_b, unsigned short* __restrict__ wi_b,
    unsigned short* __restrict__ wo_b)
{
  size_t e = ((size_t)blockIdx.x * 256 + threadIdx.x) * 8;
  if (e >= CVT_TOTAL) return;
  const float* src; unsigned short* dst; size_t off;
  if (e < IN_ELEMS)                 { src = inp; dst = inp_b; off = e; }
  else if (e < IN_ELEMS + WI_ELEMS) { src = wi;  dst = wi_b;  off = e - IN_ELEMS; }
  else                              { src = wo;  dst = wo_b;  off = e - IN_ELEMS - WI_ELEMS; }
  f32x4 a = *(const f32x4*)(src + off);
  f32x4 b = *(const f32x4*)(src + off + 4);
  us8 r;
  r[0] = f32_to_bf16(a.x); r[1] = f32_to_bf16(a.y);
  r[2] = f32_to_bf16(a.z); r[3] = f32_to_bf16(a.w);
  r[4] = f32_to_bf16(b.x); r[5] = f32_to_bf16(b.y);
  r[6] = f32_to_bf16(b.z); r[7] = f32_to_bf16(b.w);
  *(us8*)(dst + off) = r;
}

// ---------------- GEMM: C[M,N] = A[M,K](bf16) * B[N,K]^T(bf16) + bias[N] ----
// R3-proven: 256x256 tile, BK=64, 8 waves (2M x 4N). ONE barrier per phase:
// reads | stage -> BAR -> lgkm(0) -> MFMA; next phase's reads overlap laggards.
//
// MFMA operands SWAPPED (mfma(B,A)): per lane, M = lane&15 (fixed),
// N = (lane>>4)*4 + reg -> vector epilogue stores, 64B-line coalesced.
//
// Schedule (window w consumes K-tile w from buf w&1; 4 phases, 1 barrier each):
//   ph1: ds_read A0-3,B0-1 | stB(buf^1,h0,w+1) | BAR | MFMA mi0-3,ni0-1
//   ph2: ds_read A4-7      | stB(buf^1,h1,w+1) | BAR | MFMA mi4-7,ni0-1
//   ph3: ds_read B2-3      |                   | BAR | MFMA mi0-3,ni2-3
//   ph4: stA(cur,h0,w+2)+stA(cur,h1,w+2) | vmcnt(4) | BAR | MFMA mi4-7,ni2-3
// Hazards: stB into buf^1 -- last reads lgkm-drained + (w-1).ph4 BAR passed.
// stA into cur-A at ph4 -- cur-A reads end at ph2 lgkm; ph3 BAR orders all.
// vmcnt(4) keeps newest 4 (stA w+2) in flight, retires tile w+1. Tail: vmcnt(0).
#define BM 256
#define BN 256
#define BK 64

template <typename OUT>
__global__ __launch_bounds__(512, 2) void gemm256(
    const unsigned short* __restrict__ A, const unsigned short* __restrict__ Bm,
    const float* __restrict__ bias, OUT* __restrict__ C,
    int M, int N, int K)
{
  __shared__ __attribute__((aligned(16))) char lds[131072]; // [2][A 32K | B 32K]

  const int tid  = threadIdx.x;
  const int lane = tid & 63;
  const int wave = tid >> 6;
  const int wm   = wave >> 2;        // 0..1  (M half)
  const int wn   = wave & 3;         // 0..3  (N quarter)

  // bijective XCD swizzle: 256 blocks -> 8 XCDs x (8 M-tiles x 4 N-tiles)
  const int nby = M / BM;            // 64
  const int sby = nby >> 3;          // 8
  const int p   = blockIdx.x;
  const int xcd = p & 7;
  const int j   = p >> 3;
  const int by  = xcd * sby + (j % sby);
  const int bx  = j / sby;
  const int m0  = by * BM;
  const int n0  = bx * BN;

  const size_t rowb = (size_t)K * 2;  // 2048
  const int NTk = K / BK;             // 16

  // staging geometry (per 8KB round): row = tid>>3, chunk = tid&7 (16B chunks)
  // source pre-swizzle: chunk_src = chunk ^ (row&7)  [swz source, linear dest]
  const int srow  = tid >> 3;
  const int scs16 = ((tid & 7) ^ (srow & 7)) << 4;
  const char* Ab = (const char*)A;
  const char* Bb = (const char*)Bm;

  auto stA = [&](int buf, int half, int kt) {   // one half-tile = 2 x global_load_lds
    const char* g = Ab + (size_t)(m0 + half * 128 + srow) * rowb + (size_t)kt * 128 + scs16;
    char* d = lds + buf * 65536 + half * 16384 + tid * 16;
    async_load16(g, d);
    async_load16(g + 64 * rowb, d + 8192);
  };
  auto stB = [&](int buf, int half, int kt) {
    const char* g = Bb + (size_t)(n0 + half * 128 + srow) * rowb + (size_t)kt * 128 + scs16;
    char* d = lds + buf * 65536 + 32768 + half * 16384 + tid * 16;
    async_load16(g, d);
    async_load16(g + 64 * rowb, d + 8192);
  };

  // fragment read addressing; XOR term reduces to per-lane constant
  const int arow = wm * 128 + (lane & 15);
  const int brow = wn * 64  + (lane & 15);
  const int ch0  = (((lane >> 4)    ) ^ (lane & 7)) << 4;   // kk=0 swizzled chunk
  const int ch1  = (((lane >> 4) | 4) ^ (lane & 7)) << 4;   // kk=1

  f32x4 acc[8][4];
  #pragma unroll
  for (int i = 0; i < 8; ++i)
    #pragma unroll
    for (int q = 0; q < 4; ++q)
      acc[i][q] = {0.f, 0.f, 0.f, 0.f};

  // prologue: tile0 (A+B) + tile1 A-halves; vmcnt(4) => tile0 landed
  stA(0, 0, 0); stA(0, 1, 0); stB(0, 0, 0); stB(0, 1, 0);
  stA(1, 0, 1); stA(1, 1, 1);
  asm volatile("s_waitcnt vmcnt(4)" ::: "memory");
  __builtin_amdgcn_sched_barrier(0);
  __builtin_amdgcn_s_barrier();

  for (int w = 0; w < NTk; ++w) {
    const int cur = w & 1;
    const char* pa = lds + cur * 65536 + arow * 128;
    const char* pb = lds + cur * 65536 + 32768 + brow * 128;
    bf16x8 af[8][2], bfr[4][2];

    // ---------------- phase 1 ----------------
    #pragma unroll
    for (int mi = 0; mi < 4; ++mi) {
      af[mi][0] = *(const bf16x8*)(pa + mi * 2048 + ch0);
      af[mi][1] = *(const bf16x8*)(pa + mi * 2048 + ch1);
    }
    #pragma unroll
    for (int ni = 0; ni < 2; ++ni) {
      bfr[ni][0] = *(const bf16x8*)(pb + ni * 2048 + ch0);
      bfr[ni][1] = *(const bf16x8*)(pb + ni * 2048 + ch1);
    }
    if (w + 1 < NTk) stB(cur ^ 1, 0, w + 1);
    __builtin_amdgcn_s_barrier();
    asm volatile("s_waitcnt lgkmcnt(0)" ::: "memory");
    __builtin_amdgcn_sched_barrier(0);
    __builtin_amdgcn_s_setprio(1);
    #pragma unroll
    for (int mi = 0; mi < 4; ++mi)
      #pragma unroll
      for (int ni = 0; ni < 2; ++ni) {
        acc[mi][ni] = __builtin_amdgcn_mfma_f32_16x16x32_bf16(bfr[ni][0], af[mi][0], acc[mi][ni], 0, 0, 0);
        acc[mi][ni] = __builtin_amdgcn_mfma_f32_16x16x32_bf16(bfr[ni][1], af[mi][1], acc[mi][ni], 0, 0, 0);
      }
    __builtin_amdgcn_s_setprio(0);

    // ---------------- phase 2 ----------------
    #pragma unroll
    for (int mi = 4; mi < 8; ++mi) {
      af[mi][0] = *(const bf16x8*)(pa + mi * 2048 + ch0);
      af[mi][1] = *(const bf16x8*)(pa + mi * 2048 + ch1);
    }
    if (w + 1 < NTk) stB(cur ^ 1, 1, w + 1);
    __builtin_amdgcn_s_barrier();
    asm volatile("s_waitcnt lgkmcnt(0)" ::: "memory");
    __builtin_amdgcn_sched_barrier(0);
    __builtin_amdgcn_s_setprio(1);
    #pragma unroll
    for (int mi = 4; mi < 8; ++mi)
      #pragma unroll
      for (int ni = 0; ni < 2; ++ni) {
        acc[mi][ni] = __builtin_amdgcn_mfma_f32_16x16x32_bf16(bfr[ni][0], af[mi][0], acc[mi][ni], 0, 0, 0);
        acc[mi][ni] = __builtin_amdgcn_mfma_f32_16x16x32_bf16(bfr[ni][1], af[mi][1], acc[mi][ni], 0, 0, 0);
      }
    __builtin_amdgcn_s_setprio(0);

    // ---------------- phase 3 ----------------
    #pragma unroll
    for (int ni = 2; ni < 4; ++ni) {
      bfr[ni][0] = *(const bf16x8*)(pb + ni * 2048 + ch0);
      bfr[ni][1] = *(const bf16x8*)(pb + ni * 2048 + ch1);
    }
    __builtin_amdgcn_s_barrier();
    asm volatile("s_waitcnt lgkmcnt(0)" ::: "memory");
    __builtin_amdgcn_sched_barrier(0);
    __builtin_amdgcn_s_setprio(1);
    #pragma unroll
    for (int mi = 0; mi < 4; ++mi)
      #pragma unroll
      for (int ni = 2; ni < 4; ++ni) {
        acc[mi][ni] = __builtin_amdgcn_mfma_f32_16x16x32_bf16(bfr[ni][0], af[mi][0], acc[mi][ni], 0, 0, 0);
        acc[mi][ni] = __builtin_amdgcn_mfma_f32_16x16x32_bf16(bfr[ni][1], af[mi][1], acc[mi][ni], 0, 0, 0);
      }
    __builtin_amdgcn_s_setprio(0);

    // ---------------- phase 4 ----------------
    if (w + 2 < NTk) { stA(cur, 0, w + 2); stA(cur, 1, w + 2); }
    if (w < NTk - 2) asm volatile("s_waitcnt vmcnt(4)" ::: "memory");
    else             asm volatile("s_waitcnt vmcnt(0)" ::: "memory");  // tail drain
    __builtin_amdgcn_sched_barrier(0);
    __builtin_amdgcn_s_barrier();
    __builtin_amdgcn_s_setprio(1);
    #pragma unroll
    for (int mi = 4; mi < 8; ++mi)
      #pragma unroll
      for (int ni = 2; ni < 4; ++ni) {
        acc[mi][ni] = __builtin_amdgcn_mfma_f32_16x16x32_bf16(bfr[ni][0], af[mi][0], acc[mi][ni], 0, 0, 0);
        acc[mi][ni] = __builtin_amdgcn_mfma_f32_16x16x32_bf16(bfr[ni][1], af[mi][1], acc[mi][ni], 0, 0, 0);
      }
    __builtin_amdgcn_s_setprio(0);
  }

  // Epilogue (swapped-operand layout): per lane, M = base + (lane&15) fixed,
  // N = base + (lane>>4)*4 + r (4 consecutive) -> vector stores, 64B lines.
  const int q4 = (lane >> 4) * 4;
  #pragma unroll
  for (int mi = 0; mi < 8; ++mi) {
    const int row = m0 + wm * 128 + mi * 16 + (lane & 15);
    #pragma unroll
    for (int ni = 0; ni < 4; ++ni) {
      const int ncol = n0 + wn * 64 + ni * 16 + q4;
      const f32x4 bv = *(const f32x4*)(bias + ncol);
      f32x4 v = acc[mi][ni];
      v.x += bv.x; v.y += bv.y; v.z += bv.z; v.w += bv.w;
      if constexpr (sizeof(OUT) == 2) {
        u32x2 pk;
        pk.x = ((unsigned)f32_to_bf16(v.y) << 16) | (unsigned)f32_to_bf16(v.x);
        pk.y = ((unsigned)f32_to_bf16(v.w) << 16) | (unsigned)f32_to_bf16(v.z);
        *(u32x2*)((unsigned short*)C + (size_t)row * N + ncol) = pk;
      } else {
        *(f32x4*)((float*)C + (size_t)row * N + ncol) = v;
      }
    }
  }
}

// ---------------- scan phase A: per-chunk local carry (us8, 1 chunk/block) --
// Thread owns 8 consecutive u-columns (ONE us8 load = 16B/lane = 1KB/wave per
// instruction, 8 independent fma chains). Grid (NCH, B) = 256 blocks -> every
// CU active (R5's 128-block version left half the GPU idle).
__global__ __launch_bounds__(128) void scan_carry(
    const unsigned short* __restrict__ u, const float* __restrict__ params_log,
    float* __restrict__ carry)
{
  const int u0 = threadIdx.x * 8;
  const int c  = blockIdx.x;
  const int b  = blockIdx.y;
  f32x4 n0 = *(const f32x4*)(params_log + u0);
  f32x4 n1 = *(const f32x4*)(params_log + u0 + 4);
  float l[8], s[8];
  #pragma unroll
  for (int i = 0; i < 8; ++i) {
    float nv = (i < 4) ? n0[i] : n1[i - 4];
    l[i] = expf(-expf(nv));
    s[i] = 0.f;
  }
  const unsigned short* p = u + (size_t)(b * L_DIM + c * LC) * U_DIM + u0;
  #pragma unroll 8
  for (int j = 0; j < LC; ++j) {
    us8 v = *(const us8*)(p + (size_t)j * U_DIM);
    #pragma unroll
    for (int i = 0; i < 8; ++i)
      s[i] = fmaf(s[i], l[i], bf16_to_f32(v[i]));
  }
  float* cp = carry + ((size_t)b * NCH + c) * U_DIM + u0;
  f32x4 o0 = {s[0], s[1], s[2], s[3]};
  f32x4 o1 = {s[4], s[5], s[6], s[7]};
  *(f32x4*)cp = o0;
  *(f32x4*)(cp + 4) = o1;
}

// ---------------- scan phase B: prefix over chunk carries (wave-parallel) ----
// R3-proven: one wave per (b,u); lane c holds chunk-c carry; Hillis-Steele
// scan of the affine recurrence via (a,s) o (a',s') = (a*a', a*s'+s).
__global__ __launch_bounds__(256) void scan_prefix(
    const float* __restrict__ carry, const float* __restrict__ params_log,
    float* __restrict__ prefix)
{
  int wid  = (blockIdx.x * 256 + threadIdx.x) >> 6;   // wave id over B*U
  int lane = threadIdx.x & 63;
  int b  = wid >> 10;
  int uu = wid & (U_DIM - 1);
  float lp = expf(-expf(params_log[uu]) * (float)LC);
  const float* cp = carry + (size_t)b * NCH * U_DIM + uu;
  float s = cp[(size_t)lane * U_DIM];   // v_lane
  float a = lp;
  #pragma unroll
  for (int d = 1; d < 64; d <<= 1) {
    float s_up = __shfl_up(s, d, 64);
    float a_up = __shfl_up(a, d, 64);
    if (lane >= d) { s = fmaf(a, s_up, s); a *= a_up; }
  }
  float ex = __shfl_up(s, 1, 64);
  if (lane == 0) ex = 0.f;
  prefix[((size_t)b * NCH + lane) * U_DIM + uu] = ex;
}

// ---------------- scan phase C: local scan + carry-in, *gamma, bf16 out ------
// us8 load/store per j (16B/lane both ways); grid (NCH, B), 128 threads.
__global__ __launch_bounds__(128) void scan_apply(
    const unsigned short* __restrict__ u, const float* __restrict__ params_log,
    const float* __restrict__ prefix, unsigned short* __restrict__ x_b)
{
  const int u0 = threadIdx.x * 8;
  const int c  = blockIdx.x;
  const int b  = blockIdx.y;
  f32x4 n0 = *(const f32x4*)(params_log + u0);
  f32x4 n1 = *(const f32x4*)(params_log + u0 + 4);
  f32x4 g0 = *(const f32x4*)(params_log + U_DIM + u0);
  f32x4 g1 = *(const f32x4*)(params_log + U_DIM + u0 + 4);
  const float* pp = prefix + ((size_t)b * NCH + c) * U_DIM + u0;
  f32x4 s0 = *(const f32x4*)pp;
  f32x4 s1 = *(const f32x4*)(pp + 4);
  float l[8], g[8], s[8];
  #pragma unroll
  for (int i = 0; i < 8; ++i) {
    float nv = (i < 4) ? n0[i] : n1[i - 4];
    l[i] = expf(-expf(nv));
    g[i] = expf((i < 4) ? g0[i] : g1[i - 4]);
    s[i] = (i < 4) ? s0[i] : s1[i - 4];
  }
  const unsigned short* p = u + (size_t)(b * L_DIM + c * LC) * U_DIM + u0;
  unsigned short* q = x_b + (size_t)(b * L_DIM + c * LC) * U_DIM + u0;
  #pragma unroll 8
  for (int j = 0; j < LC; ++j) {
    us8 v = *(const us8*)(p + (size_t)j * U_DIM);
    us8 o;
    #pragma unroll
    for (int i = 0; i < 8; ++i) {
      s[i] = fmaf(s[i], l[i], bf16_to_f32(v[i]));
      o[i] = f32_to_bf16(s[i] * g[i]);
    }
    *(us8*)(q + (size_t)j * U_DIM) = o;
  }
}

extern "C" void kernel_launch(void* const* d_in, const int* in_sizes, int n_in,
                              void* d_out, int out_size, void* d_ws, size_t ws_size,
                              hipStream_t stream)
{
  const float* inputs     = (const float*)d_in[0];   // (B, L, H)
  const float* Wi         = (const float*)d_in[1];   // (U, H)
  const float* bi         = (const float*)d_in[2];   // (U,)
  const float* Wo         = (const float*)d_in[3];   // (H, U)
  const float* bo         = (const float*)d_in[4];   // (H,)
  const float* params_log = (const float*)d_in[5];   // (2, U)
  float* out = (float*)d_out;                        // (B, L, H) fp32

  char* ws = (char*)d_ws;
  unsigned short* u_b    = (unsigned short*)(ws);                 // 32 MB bf16 u
  unsigned short* x_b    = (unsigned short*)(ws + (32u << 20));   // 32 MB bf16 x
  unsigned short* in_b   = (unsigned short*)(ws + (64u << 20));   // 32 MB bf16 inputs
  unsigned short* wi_b   = (unsigned short*)(ws + (96u << 20));   //  2 MB bf16 Wi
  unsigned short* wo_b   = (unsigned short*)(ws + (98u << 20));   //  2 MB bf16 Wo
  float*          carry  = (float*)(ws + (100u << 20));           //  1 MB
  float*          prefix = (float*)(ws + (101u << 20));           //  1 MB

  cvt_all<<<dim3((CVT_TOTAL / 8 + 255) / 256), 256, 0, stream>>>(
      inputs, Wi, Wo, in_b, wi_b, wo_b);

  // GEMM1: u = inputs @ Wi^T + bi   (M=16384, N=U, K=H) -> bf16
  gemm256<unsigned short><<<dim3((M_DIM / BM) * (U_DIM / BN)), 512, 0, stream>>>(
      in_b, wi_b, bi, u_b, M_DIM, U_DIM, H_DIM);

  scan_carry <<<dim3(NCH, B_DIM), 128, 0, stream>>>(u_b, params_log, carry);
  scan_prefix<<<dim3(B_DIM * U_DIM * 64 / 256), 256, 0, stream>>>(carry, params_log, prefix);
  scan_apply <<<dim3(NCH, B_DIM), 128, 0, stream>>>(u_b, params_log, prefix, x_b);

  // GEMM2: out = x @ Wo^T + bo   (M=16384, N=H, K=U) -> fp32
  gemm256<float><<<dim3((M_DIM / BM) * (H_DIM / BN)), 512, 0, stream>>>(
      x_b, wo_b, bo, out, M_DIM, H_DIM, U_DIM);
}

// Round 7
// 228.015 us; speedup vs baseline: 1.0575x; 1.0575x over previous
//
#include <hip/hip_runtime.h>

#define B_DIM 4
#define L_DIM 4096
#define H_DIM 1024
#define U_DIM 1024
#define M_DIM (B_DIM * L_DIM)   // 16384
#define LC 64                    // scan chunk length
#define NCH (L_DIM / LC)         // 64 chunks per sequence

using f32x4  = __attribute__((ext_vector_type(4))) float;
using bf16x8 = __attribute__((ext_vector_type(8))) __bf16;
using us8    = __attribute__((ext_vector_type(8))) unsigned short;
using u32x2  = __attribute__((ext_vector_type(2))) unsigned int;

__device__ inline unsigned short f32_to_bf16(float f) {
  unsigned int u = __float_as_uint(f);
  u += 0x7FFF + ((u >> 16) & 1);   // round-to-nearest-even
  return (unsigned short)(u >> 16);
}
__device__ inline float bf16_to_f32(unsigned short v) {
  return __uint_as_float((unsigned int)v << 16);
}

__device__ inline void async_load16(const void* g, void* l) {
  // gfx950 global->LDS direct, 16B/lane; LDS dest = wave-uniform base + lane*16.
  __builtin_amdgcn_global_load_lds(
      (const __attribute__((address_space(1))) void*)g,
      (__attribute__((address_space(3))) void*)l, 16, 0, 0);
}

// ---------------- fused fp32 -> bf16 convert: inputs, Wi, Wo ----------------
#define IN_ELEMS  (M_DIM * H_DIM)          // 16777216
#define WI_ELEMS  (U_DIM * H_DIM)          // 1048576
#define WO_ELEMS  (H_DIM * U_DIM)          // 1048576
#define CVT_TOTAL (IN_ELEMS + WI_ELEMS + WO_ELEMS)

__global__ __launch_bounds__(256) void cvt_all(
    const float* __restrict__ inp, const float* __restrict__ wi,
    const float* __restrict__ wo,
    unsigned short* __restrict__ inp_b, unsigned short* __restrict__ wi_b,
    unsigned short* __restrict__ wo_b)
{
  size_t e = ((size_t)blockIdx.x * 256 + threadIdx.x) * 8;
  if (e >= CVT_TOTAL) return;
  const float* src; unsigned short* dst; size_t off;
  if (e < IN_ELEMS)                 { src = inp; dst = inp_b; off = e; }
  else if (e < IN_ELEMS + WI_ELEMS) { src = wi;  dst = wi_b;  off = e - IN_ELEMS; }
  else                              { src = wo;  dst = wo_b;  off = e - IN_ELEMS - WI_ELEMS; }
  f32x4 a = *(const f32x4*)(src + off);
  f32x4 b = *(const f32x4*)(src + off + 4);
  us8 r;
  r[0] = f32_to_bf16(a.x); r[1] = f32_to_bf16(a.y);
  r[2] = f32_to_bf16(a.z); r[3] = f32_to_bf16(a.w);
  r[4] = f32_to_bf16(b.x); r[5] = f32_to_bf16(b.y);
  r[6] = f32_to_bf16(b.z); r[7] = f32_to_bf16(b.w);
  *(us8*)(dst + off) = r;
}

// ---------------- GEMM: C[M,N] = A[M,K](bf16) * B[N,K]^T(bf16) + bias[N] ----
// R3-proven: 256x256 tile, BK=64, 8 waves (2M x 4N). ONE barrier per phase:
// reads | stage -> BAR -> lgkm(0) -> MFMA; next phase's reads overlap laggards.
//
// MFMA operands SWAPPED (mfma(B,A)): per lane, M = lane&15 (fixed),
// N = (lane>>4)*4 + reg -> vector epilogue stores, 64B-line coalesced.
//
// Schedule (window w consumes K-tile w from buf w&1; 4 phases, 1 barrier each):
//   ph1: ds_read A0-3,B0-1 | stB(buf^1,h0,w+1) | BAR | MFMA mi0-3,ni0-1
//   ph2: ds_read A4-7      | stB(buf^1,h1,w+1) | BAR | MFMA mi4-7,ni0-1
//   ph3: ds_read B2-3      |                   | BAR | MFMA mi0-3,ni2-3
//   ph4: stA(cur,h0,w+2)+stA(cur,h1,w+2) | vmcnt(4) | BAR | MFMA mi4-7,ni2-3
// Hazards: stB into buf^1 -- last reads lgkm-drained + (w-1).ph4 BAR passed.
// stA into cur-A at ph4 -- cur-A reads end at ph2 lgkm; ph3 BAR orders all.
// vmcnt(4) keeps newest 4 (stA w+2) in flight, retires tile w+1. Tail: vmcnt(0).
#define BM 256
#define BN 256
#define BK 64

template <typename OUT>
__global__ __launch_bounds__(512, 2) void gemm256(
    const unsigned short* __restrict__ A, const unsigned short* __restrict__ Bm,
    const float* __restrict__ bias, OUT* __restrict__ C,
    int M, int N, int K)
{
  __shared__ __attribute__((aligned(16))) char lds[131072]; // [2][A 32K | B 32K]

  const int tid  = threadIdx.x;
  const int lane = tid & 63;
  const int wave = tid >> 6;
  const int wm   = wave >> 2;        // 0..1  (M half)
  const int wn   = wave & 3;         // 0..3  (N quarter)

  // bijective XCD swizzle: 256 blocks -> 8 XCDs x (8 M-tiles x 4 N-tiles)
  const int nby = M / BM;            // 64
  const int sby = nby >> 3;          // 8
  const int p   = blockIdx.x;
  const int xcd = p & 7;
  const int j   = p >> 3;
  const int by  = xcd * sby + (j % sby);
  const int bx  = j / sby;
  const int m0  = by * BM;
  const int n0  = bx * BN;

  const size_t rowb = (size_t)K * 2;  // 2048
  const int NTk = K / BK;             // 16

  // staging geometry (per 8KB round): row = tid>>3, chunk = tid&7 (16B chunks)
  // source pre-swizzle: chunk_src = chunk ^ (row&7)  [swz source, linear dest]
  const int srow  = tid >> 3;
  const int scs16 = ((tid & 7) ^ (srow & 7)) << 4;
  const char* Ab = (const char*)A;
  const char* Bb = (const char*)Bm;

  auto stA = [&](int buf, int half, int kt) {   // one half-tile = 2 x global_load_lds
    const char* g = Ab + (size_t)(m0 + half * 128 + srow) * rowb + (size_t)kt * 128 + scs16;
    char* d = lds + buf * 65536 + half * 16384 + tid * 16;
    async_load16(g, d);
    async_load16(g + 64 * rowb, d + 8192);
  };
  auto stB = [&](int buf, int half, int kt) {
    const char* g = Bb + (size_t)(n0 + half * 128 + srow) * rowb + (size_t)kt * 128 + scs16;
    char* d = lds + buf * 65536 + 32768 + half * 16384 + tid * 16;
    async_load16(g, d);
    async_load16(g + 64 * rowb, d + 8192);
  };

  // fragment read addressing; XOR term reduces to per-lane constant
  const int arow = wm * 128 + (lane & 15);
  const int brow = wn * 64  + (lane & 15);
  const int ch0  = (((lane >> 4)    ) ^ (lane & 7)) << 4;   // kk=0 swizzled chunk
  const int ch1  = (((lane >> 4) | 4) ^ (lane & 7)) << 4;   // kk=1

  f32x4 acc[8][4];
  #pragma unroll
  for (int i = 0; i < 8; ++i)
    #pragma unroll
    for (int q = 0; q < 4; ++q)
      acc[i][q] = {0.f, 0.f, 0.f, 0.f};

  // prologue: tile0 (A+B) + tile1 A-halves; vmcnt(4) => tile0 landed
  stA(0, 0, 0); stA(0, 1, 0); stB(0, 0, 0); stB(0, 1, 0);
  stA(1, 0, 1); stA(1, 1, 1);
  asm volatile("s_waitcnt vmcnt(4)" ::: "memory");
  __builtin_amdgcn_sched_barrier(0);
  __builtin_amdgcn_s_barrier();

  for (int w = 0; w < NTk; ++w) {
    const int cur = w & 1;
    const char* pa = lds + cur * 65536 + arow * 128;
    const char* pb = lds + cur * 65536 + 32768 + brow * 128;
    bf16x8 af[8][2], bfr[4][2];

    // ---------------- phase 1 ----------------
    #pragma unroll
    for (int mi = 0; mi < 4; ++mi) {
      af[mi][0] = *(const bf16x8*)(pa + mi * 2048 + ch0);
      af[mi][1] = *(const bf16x8*)(pa + mi * 2048 + ch1);
    }
    #pragma unroll
    for (int ni = 0; ni < 2; ++ni) {
      bfr[ni][0] = *(const bf16x8*)(pb + ni * 2048 + ch0);
      bfr[ni][1] = *(const bf16x8*)(pb + ni * 2048 + ch1);
    }
    if (w + 1 < NTk) stB(cur ^ 1, 0, w + 1);
    __builtin_amdgcn_s_barrier();
    asm volatile("s_waitcnt lgkmcnt(0)" ::: "memory");
    __builtin_amdgcn_sched_barrier(0);
    __builtin_amdgcn_s_setprio(1);
    #pragma unroll
    for (int mi = 0; mi < 4; ++mi)
      #pragma unroll
      for (int ni = 0; ni < 2; ++ni) {
        acc[mi][ni] = __builtin_amdgcn_mfma_f32_16x16x32_bf16(bfr[ni][0], af[mi][0], acc[mi][ni], 0, 0, 0);
        acc[mi][ni] = __builtin_amdgcn_mfma_f32_16x16x32_bf16(bfr[ni][1], af[mi][1], acc[mi][ni], 0, 0, 0);
      }
    __builtin_amdgcn_s_setprio(0);

    // ---------------- phase 2 ----------------
    #pragma unroll
    for (int mi = 4; mi < 8; ++mi) {
      af[mi][0] = *(const bf16x8*)(pa + mi * 2048 + ch0);
      af[mi][1] = *(const bf16x8*)(pa + mi * 2048 + ch1);
    }
    if (w + 1 < NTk) stB(cur ^ 1, 1, w + 1);
    __builtin_amdgcn_s_barrier();
    asm volatile("s_waitcnt lgkmcnt(0)" ::: "memory");
    __builtin_amdgcn_sched_barrier(0);
    __builtin_amdgcn_s_setprio(1);
    #pragma unroll
    for (int mi = 4; mi < 8; ++mi)
      #pragma unroll
      for (int ni = 0; ni < 2; ++ni) {
        acc[mi][ni] = __builtin_amdgcn_mfma_f32_16x16x32_bf16(bfr[ni][0], af[mi][0], acc[mi][ni], 0, 0, 0);
        acc[mi][ni] = __builtin_amdgcn_mfma_f32_16x16x32_bf16(bfr[ni][1], af[mi][1], acc[mi][ni], 0, 0, 0);
      }
    __builtin_amdgcn_s_setprio(0);

    // ---------------- phase 3 ----------------
    #pragma unroll
    for (int ni = 2; ni < 4; ++ni) {
      bfr[ni][0] = *(const bf16x8*)(pb + ni * 2048 + ch0);
      bfr[ni][1] = *(const bf16x8*)(pb + ni * 2048 + ch1);
    }
    __builtin_amdgcn_s_barrier();
    asm volatile("s_waitcnt lgkmcnt(0)" ::: "memory");
    __builtin_amdgcn_sched_barrier(0);
    __builtin_amdgcn_s_setprio(1);
    #pragma unroll
    for (int mi = 0; mi < 4; ++mi)
      #pragma unroll
      for (int ni = 2; ni < 4; ++ni) {
        acc[mi][ni] = __builtin_amdgcn_mfma_f32_16x16x32_bf16(bfr[ni][0], af[mi][0], acc[mi][ni], 0, 0, 0);
        acc[mi][ni] = __builtin_amdgcn_mfma_f32_16x16x32_bf16(bfr[ni][1], af[mi][1], acc[mi][ni], 0, 0, 0);
      }
    __builtin_amdgcn_s_setprio(0);

    // ---------------- phase 4 ----------------
    if (w + 2 < NTk) { stA(cur, 0, w + 2); stA(cur, 1, w + 2); }
    if (w < NTk - 2) asm volatile("s_waitcnt vmcnt(4)" ::: "memory");
    else             asm volatile("s_waitcnt vmcnt(0)" ::: "memory");  // tail drain
    __builtin_amdgcn_sched_barrier(0);
    __builtin_amdgcn_s_barrier();
    __builtin_amdgcn_s_setprio(1);
    #pragma unroll
    for (int mi = 4; mi < 8; ++mi)
      #pragma unroll
      for (int ni = 2; ni < 4; ++ni) {
        acc[mi][ni] = __builtin_amdgcn_mfma_f32_16x16x32_bf16(bfr[ni][0], af[mi][0], acc[mi][ni], 0, 0, 0);
        acc[mi][ni] = __builtin_amdgcn_mfma_f32_16x16x32_bf16(bfr[ni][1], af[mi][1], acc[mi][ni], 0, 0, 0);
      }
    __builtin_amdgcn_s_setprio(0);
  }

  // Epilogue (swapped-operand layout): per lane, M = base + (lane&15) fixed,
  // N = base + (lane>>4)*4 + r (4 consecutive) -> vector stores, 64B lines.
  const int q4 = (lane >> 4) * 4;
  #pragma unroll
  for (int mi = 0; mi < 8; ++mi) {
    const int row = m0 + wm * 128 + mi * 16 + (lane & 15);
    #pragma unroll
    for (int ni = 0; ni < 4; ++ni) {
      const int ncol = n0 + wn * 64 + ni * 16 + q4;
      const f32x4 bv = *(const f32x4*)(bias + ncol);
      f32x4 v = acc[mi][ni];
      v.x += bv.x; v.y += bv.y; v.z += bv.z; v.w += bv.w;
      if constexpr (sizeof(OUT) == 2) {
        u32x2 pk;
        pk.x = ((unsigned)f32_to_bf16(v.y) << 16) | (unsigned)f32_to_bf16(v.x);
        pk.y = ((unsigned)f32_to_bf16(v.w) << 16) | (unsigned)f32_to_bf16(v.z);
        *(u32x2*)((unsigned short*)C + (size_t)row * N + ncol) = pk;
      } else {
        *(f32x4*)((float*)C + (size_t)row * N + ncol) = v;
      }
    }
  }
}

// ---------------- scan phase A: per-chunk local carry (bf16 u) ---------------
// R3-proven layout: 1024 blocks x 256 thr (16 waves/CU TLP); wave reads 64
// consecutive u-columns at each row j -> coalesced 128B/wave-instruction.
// Empirically beats 16B/lane variants with fewer waves (R5/R6 regressions).
__global__ __launch_bounds__(256) void scan_carry(
    const unsigned short* __restrict__ u, const float* __restrict__ params_log,
    float* __restrict__ carry)
{
  int uu = blockIdx.x * 256 + threadIdx.x;
  int c  = blockIdx.y;
  int b  = blockIdx.z;
  float l = expf(-expf(params_log[uu]));
  const unsigned short* p = u + (size_t)(b * L_DIM + c * LC) * U_DIM + uu;
  float s = 0.f;
  #pragma unroll 8
  for (int j = 0; j < LC; ++j)
    s = fmaf(s, l, bf16_to_f32(p[(size_t)j * U_DIM]));
  carry[((size_t)b * NCH + c) * U_DIM + uu] = s;
}

// ---------------- scan phase B: prefix over chunk carries (wave-parallel) ----
// R3-proven: one wave per (b,u); lane c holds chunk-c carry; Hillis-Steele
// scan of the affine recurrence via (a,s) o (a',s') = (a*a', a*s'+s).
__global__ __launch_bounds__(256) void scan_prefix(
    const float* __restrict__ carry, const float* __restrict__ params_log,
    float* __restrict__ prefix)
{
  int wid  = (blockIdx.x * 256 + threadIdx.x) >> 6;   // wave id over B*U
  int lane = threadIdx.x & 63;
  int b  = wid >> 10;
  int uu = wid & (U_DIM - 1);
  float lp = expf(-expf(params_log[uu]) * (float)LC);
  const float* cp = carry + (size_t)b * NCH * U_DIM + uu;
  float s = cp[(size_t)lane * U_DIM];   // v_lane
  float a = lp;
  #pragma unroll
  for (int d = 1; d < 64; d <<= 1) {
    float s_up = __shfl_up(s, d, 64);
    float a_up = __shfl_up(a, d, 64);
    if (lane >= d) { s = fmaf(a, s_up, s); a *= a_up; }
  }
  float ex = __shfl_up(s, 1, 64);
  if (lane == 0) ex = 0.f;
  prefix[((size_t)b * NCH + lane) * U_DIM + uu] = ex;
}

// ---------------- scan phase C: local scan + carry-in, *gamma, bf16 out ------
// R3-proven layout: 1024 blocks x 256 thr, coalesced scalar stream.
__global__ __launch_bounds__(256) void scan_apply(
    const unsigned short* __restrict__ u, const float* __restrict__ params_log,
    const float* __restrict__ prefix, unsigned short* __restrict__ x_b)
{
  int uu = blockIdx.x * 256 + threadIdx.x;
  int c  = blockIdx.y;
  int b  = blockIdx.z;
  float l = expf(-expf(params_log[uu]));
  float g = expf(params_log[U_DIM + uu]);
  float s = prefix[((size_t)b * NCH + c) * U_DIM + uu];
  const unsigned short* p = u + (size_t)(b * L_DIM + c * LC) * U_DIM + uu;
  unsigned short* q = x_b + (size_t)(b * L_DIM + c * LC) * U_DIM + uu;
  #pragma unroll 8
  for (int j = 0; j < LC; ++j) {
    s = fmaf(s, l, bf16_to_f32(p[(size_t)j * U_DIM]));
    q[(size_t)j * U_DIM] = f32_to_bf16(s * g);
  }
}

extern "C" void kernel_launch(void* const* d_in, const int* in_sizes, int n_in,
                              void* d_out, int out_size, void* d_ws, size_t ws_size,
                              hipStream_t stream)
{
  const float* inputs     = (const float*)d_in[0];   // (B, L, H)
  const float* Wi         = (const float*)d_in[1];   // (U, H)
  const float* bi         = (const float*)d_in[2];   // (U,)
  const float* Wo         = (const float*)d_in[3];   // (H, U)
  const float* bo         = (const float*)d_in[4];   // (H,)
  const float* params_log = (const float*)d_in[5];   // (2, U)
  float* out = (float*)d_out;                        // (B, L, H) fp32

  char* ws = (char*)d_ws;
  unsigned short* u_b    = (unsigned short*)(ws);                 // 32 MB bf16 u
  unsigned short* x_b    = (unsigned short*)(ws + (32u << 20));   // 32 MB bf16 x
  unsigned short* in_b   = (unsigned short*)(ws + (64u << 20));   // 32 MB bf16 inputs
  unsigned short* wi_b   = (unsigned short*)(ws + (96u << 20));   //  2 MB bf16 Wi
  unsigned short* wo_b   = (unsigned short*)(ws + (98u << 20));   //  2 MB bf16 Wo
  float*          carry  = (float*)(ws + (100u << 20));           //  1 MB
  float*          prefix = (float*)(ws + (101u << 20));           //  1 MB

  cvt_all<<<dim3((CVT_TOTAL / 8 + 255) / 256), 256, 0, stream>>>(
      inputs, Wi, Wo, in_b, wi_b, wo_b);

  // GEMM1: u = inputs @ Wi^T + bi   (M=16384, N=U, K=H) -> bf16
  gemm256<unsigned short><<<dim3((M_DIM / BM) * (U_DIM / BN)), 512, 0, stream>>>(
      in_b, wi_b, bi, u_b, M_DIM, U_DIM, H_DIM);

  scan_carry <<<dim3(U_DIM / 256, NCH, B_DIM), 256, 0, stream>>>(u_b, params_log, carry);
  scan_prefix<<<dim3(B_DIM * U_DIM * 64 / 256), 256, 0, stream>>>(carry, params_log, prefix);
  scan_apply <<<dim3(U_DIM / 256, NCH, B_DIM), 256, 0, stream>>>(u_b, params_log, prefix, x_b);

  // GEMM2: out = x @ Wo^T + bo   (M=16384, N=H, K=U) -> fp32
  gemm256<float><<<dim3((M_DIM / BM) * (H_DIM / BN)), 512, 0, stream>>>(
      x_b, wo_b, bo, out, M_DIM, H_DIM, U_DIM);
}

// Round 9
// 224.802 us; speedup vs baseline: 1.0726x; 1.0143x over previous
//
#include <hip/hip_runtime.h>

#define B_DIM 4
#define L_DIM 4096
#define H_DIM 1024
#define U_DIM 1024
#define M_DIM (B_DIM * L_DIM)   // 16384
#define LC 64                    // scan chunk length
#define NCH (L_DIM / LC)         // 64 chunks per sequence

using f32x4  = __attribute__((ext_vector_type(4))) float;
using bf16x8 = __attribute__((ext_vector_type(8))) __bf16;
using us8    = __attribute__((ext_vector_type(8))) unsigned short;
using u32x2  = __attribute__((ext_vector_type(2))) unsigned int;

__device__ inline unsigned short f32_to_bf16(float f) {
  unsigned int u = __float_as_uint(f);
  u += 0x7FFF + ((u >> 16) & 1);   // round-to-nearest-even
  return (unsigned short)(u >> 16);
}
__device__ inline float bf16_to_f32(unsigned short v) {
  return __uint_as_float((unsigned int)v << 16);
}

__device__ inline void async_load16(const void* g, void* l) {
  // gfx950 global->LDS direct, 16B/lane; LDS dest = wave-uniform base + lane*16.
  __builtin_amdgcn_global_load_lds(
      (const __attribute__((address_space(1))) void*)g,
      (__attribute__((address_space(3))) void*)l, 16, 0, 0);
}

// ---------------- fused fp32 -> bf16 convert: inputs, Wi, Wo ----------------
#define IN_ELEMS  (M_DIM * H_DIM)          // 16777216
#define WI_ELEMS  (U_DIM * H_DIM)          // 1048576
#define WO_ELEMS  (H_DIM * U_DIM)          // 1048576
#define CVT_TOTAL (IN_ELEMS + WI_ELEMS + WO_ELEMS)

__global__ __launch_bounds__(256) void cvt_all(
    const float* __restrict__ inp, const float* __restrict__ wi,
    const float* __restrict__ wo,
    unsigned short* __restrict__ inp_b, unsigned short* __restrict__ wi_b,
    unsigned short* __restrict__ wo_b)
{
  size_t e = ((size_t)blockIdx.x * 256 + threadIdx.x) * 8;
  if (e >= CVT_TOTAL) return;
  const float* src; unsigned short* dst; size_t off;
  if (e < IN_ELEMS)                 { src = inp; dst = inp_b; off = e; }
  else if (e < IN_ELEMS + WI_ELEMS) { src = wi;  dst = wi_b;  off = e - IN_ELEMS; }
  else                              { src = wo;  dst = wo_b;  off = e - IN_ELEMS - WI_ELEMS; }
  f32x4 a = *(const f32x4*)(src + off);
  f32x4 b = *(const f32x4*)(src + off + 4);
  us8 r;
  r[0] = f32_to_bf16(a.x); r[1] = f32_to_bf16(a.y);
  r[2] = f32_to_bf16(a.z); r[3] = f32_to_bf16(a.w);
  r[4] = f32_to_bf16(b.x); r[5] = f32_to_bf16(b.y);
  r[6] = f32_to_bf16(b.z); r[7] = f32_to_bf16(b.w);
  *(us8*)(dst + off) = r;
}

// ---------------- GEMM: C[M,N] = A[M,K](bf16) * B[N,K]^T(bf16) + bias[N] ----
// R3-proven: 256x256 tile, BK=64, 8 waves (2M x 4N). ONE barrier per phase:
// reads | stage -> BAR -> lgkm(0) -> MFMA; next phase's reads overlap laggards.
//
// MFMA operands SWAPPED (mfma(B,A)): per lane, M = lane&15 (fixed),
// N = (lane>>4)*4 + reg -> vector epilogue stores, 64B-line coalesced.
//
// Schedule (window w consumes K-tile w from buf w&1; 4 phases, 1 barrier each):
//   ph1: ds_read A0-3,B0-1 | stB(buf^1,h0,w+1) | BAR | MFMA mi0-3,ni0-1
//   ph2: ds_read A4-7      | stB(buf^1,h1,w+1) | BAR | MFMA mi4-7,ni0-1
//   ph3: ds_read B2-3      |                   | BAR | MFMA mi0-3,ni2-3
//   ph4: stA(cur,h0,w+2)+stA(cur,h1,w+2) | vmcnt(4) | BAR | MFMA mi4-7,ni2-3
// Hazards: stB into buf^1 -- last reads lgkm-drained + (w-1).ph4 BAR passed.
// stA into cur-A at ph4 -- cur-A reads end at ph2 lgkm; ph3 BAR orders all.
// vmcnt(4) keeps newest 4 (stA w+2) in flight, retires tile w+1. Tail: vmcnt(0).
#define BM 256
#define BN 256
#define BK 64

template <typename OUT>
__global__ __launch_bounds__(512, 2) void gemm256(
    const unsigned short* __restrict__ A, const unsigned short* __restrict__ Bm,
    const float* __restrict__ bias, OUT* __restrict__ C,
    int M, int N, int K)
{
  __shared__ __attribute__((aligned(16))) char lds[131072]; // [2][A 32K | B 32K]

  const int tid  = threadIdx.x;
  const int lane = tid & 63;
  const int wave = tid >> 6;
  const int wm   = wave >> 2;        // 0..1  (M half)
  const int wn   = wave & 3;         // 0..3  (N quarter)

  // bijective XCD swizzle: 256 blocks -> 8 XCDs x (8 M-tiles x 4 N-tiles)
  const int nby = M / BM;            // 64
  const int sby = nby >> 3;          // 8
  const int p   = blockIdx.x;
  const int xcd = p & 7;
  const int j   = p >> 3;
  const int by  = xcd * sby + (j % sby);
  const int bx  = j / sby;
  const int m0  = by * BM;
  const int n0  = bx * BN;

  const size_t rowb = (size_t)K * 2;  // 2048
  const int NTk = K / BK;             // 16

  // staging geometry (per 8KB round): row = tid>>3, chunk = tid&7 (16B chunks)
  // source pre-swizzle: chunk_src = chunk ^ (row&7)  [swz source, linear dest]
  const int srow  = tid >> 3;
  const int scs16 = ((tid & 7) ^ (srow & 7)) << 4;
  const char* Ab = (const char*)A;
  const char* Bb = (const char*)Bm;

  auto stA = [&](int buf, int half, int kt) {   // one half-tile = 2 x global_load_lds
    const char* g = Ab + (size_t)(m0 + half * 128 + srow) * rowb + (size_t)kt * 128 + scs16;
    char* d = lds + buf * 65536 + half * 16384 + tid * 16;
    async_load16(g, d);
    async_load16(g + 64 * rowb, d + 8192);
  };
  auto stB = [&](int buf, int half, int kt) {
    const char* g = Bb + (size_t)(n0 + half * 128 + srow) * rowb + (size_t)kt * 128 + scs16;
    char* d = lds + buf * 65536 + 32768 + half * 16384 + tid * 16;
    async_load16(g, d);
    async_load16(g + 64 * rowb, d + 8192);
  };

  // fragment read addressing; XOR term reduces to per-lane constant
  const int arow = wm * 128 + (lane & 15);
  const int brow = wn * 64  + (lane & 15);
  const int ch0  = (((lane >> 4)    ) ^ (lane & 7)) << 4;   // kk=0 swizzled chunk
  const int ch1  = (((lane >> 4) | 4) ^ (lane & 7)) << 4;   // kk=1

  f32x4 acc[8][4];
  #pragma unroll
  for (int i = 0; i < 8; ++i)
    #pragma unroll
    for (int q = 0; q < 4; ++q)
      acc[i][q] = {0.f, 0.f, 0.f, 0.f};

  // prologue: tile0 (A+B) + tile1 A-halves; vmcnt(4) => tile0 landed
  stA(0, 0, 0); stA(0, 1, 0); stB(0, 0, 0); stB(0, 1, 0);
  stA(1, 0, 1); stA(1, 1, 1);
  asm volatile("s_waitcnt vmcnt(4)" ::: "memory");
  __builtin_amdgcn_sched_barrier(0);
  __builtin_amdgcn_s_barrier();

  for (int w = 0; w < NTk; ++w) {
    const int cur = w & 1;
    const char* pa = lds + cur * 65536 + arow * 128;
    const char* pb = lds + cur * 65536 + 32768 + brow * 128;
    bf16x8 af[8][2], bfr[4][2];

    // ---------------- phase 1 ----------------
    #pragma unroll
    for (int mi = 0; mi < 4; ++mi) {
      af[mi][0] = *(const bf16x8*)(pa + mi * 2048 + ch0);
      af[mi][1] = *(const bf16x8*)(pa + mi * 2048 + ch1);
    }
    #pragma unroll
    for (int ni = 0; ni < 2; ++ni) {
      bfr[ni][0] = *(const bf16x8*)(pb + ni * 2048 + ch0);
      bfr[ni][1] = *(const bf16x8*)(pb + ni * 2048 + ch1);
    }
    if (w + 1 < NTk) stB(cur ^ 1, 0, w + 1);
    __builtin_amdgcn_s_barrier();
    asm volatile("s_waitcnt lgkmcnt(0)" ::: "memory");
    __builtin_amdgcn_sched_barrier(0);
    __builtin_amdgcn_s_setprio(1);
    #pragma unroll
    for (int mi = 0; mi < 4; ++mi)
      #pragma unroll
      for (int ni = 0; ni < 2; ++ni) {
        acc[mi][ni] = __builtin_amdgcn_mfma_f32_16x16x32_bf16(bfr[ni][0], af[mi][0], acc[mi][ni], 0, 0, 0);
        acc[mi][ni] = __builtin_amdgcn_mfma_f32_16x16x32_bf16(bfr[ni][1], af[mi][1], acc[mi][ni], 0, 0, 0);
      }
    __builtin_amdgcn_s_setprio(0);

    // ---------------- phase 2 ----------------
    #pragma unroll
    for (int mi = 4; mi < 8; ++mi) {
      af[mi][0] = *(const bf16x8*)(pa + mi * 2048 + ch0);
      af[mi][1] = *(const bf16x8*)(pa + mi * 2048 + ch1);
    }
    if (w + 1 < NTk) stB(cur ^ 1, 1, w + 1);
    __builtin_amdgcn_s_barrier();
    asm volatile("s_waitcnt lgkmcnt(0)" ::: "memory");
    __builtin_amdgcn_sched_barrier(0);
    __builtin_amdgcn_s_setprio(1);
    #pragma unroll
    for (int mi = 4; mi < 8; ++mi)
      #pragma unroll
      for (int ni = 0; ni < 2; ++ni) {
        acc[mi][ni] = __builtin_amdgcn_mfma_f32_16x16x32_bf16(bfr[ni][0], af[mi][0], acc[mi][ni], 0, 0, 0);
        acc[mi][ni] = __builtin_amdgcn_mfma_f32_16x16x32_bf16(bfr[ni][1], af[mi][1], acc[mi][ni], 0, 0, 0);
      }
    __builtin_amdgcn_s_setprio(0);

    // ---------------- phase 3 ----------------
    #pragma unroll
    for (int ni = 2; ni < 4; ++ni) {
      bfr[ni][0] = *(const bf16x8*)(pb + ni * 2048 + ch0);
      bfr[ni][1] = *(const bf16x8*)(pb + ni * 2048 + ch1);
    }
    __builtin_amdgcn_s_barrier();
    asm volatile("s_waitcnt lgkmcnt(0)" ::: "memory");
    __builtin_amdgcn_sched_barrier(0);
    __builtin_amdgcn_s_setprio(1);
    #pragma unroll
    for (int mi = 0; mi < 4; ++mi)
      #pragma unroll
      for (int ni = 2; ni < 4; ++ni) {
        acc[mi][ni] = __builtin_amdgcn_mfma_f32_16x16x32_bf16(bfr[ni][0], af[mi][0], acc[mi][ni], 0, 0, 0);
        acc[mi][ni] = __builtin_amdgcn_mfma_f32_16x16x32_bf16(bfr[ni][1], af[mi][1], acc[mi][ni], 0, 0, 0);
      }
    __builtin_amdgcn_s_setprio(0);

    // ---------------- phase 4 ----------------
    if (w + 2 < NTk) { stA(cur, 0, w + 2); stA(cur, 1, w + 2); }
    if (w < NTk - 2) asm volatile("s_waitcnt vmcnt(4)" ::: "memory");
    else             asm volatile("s_waitcnt vmcnt(0)" ::: "memory");  // tail drain
    __builtin_amdgcn_sched_barrier(0);
    __builtin_amdgcn_s_barrier();
    __builtin_amdgcn_s_setprio(1);
    #pragma unroll
    for (int mi = 4; mi < 8; ++mi)
      #pragma unroll
      for (int ni = 2; ni < 4; ++ni) {
        acc[mi][ni] = __builtin_amdgcn_mfma_f32_16x16x32_bf16(bfr[ni][0], af[mi][0], acc[mi][ni], 0, 0, 0);
        acc[mi][ni] = __builtin_amdgcn_mfma_f32_16x16x32_bf16(bfr[ni][1], af[mi][1], acc[mi][ni], 0, 0, 0);
      }
    __builtin_amdgcn_s_setprio(0);
  }

  // Epilogue (swapped-operand layout): per lane, M = base + (lane&15) fixed,
  // N = base + (lane>>4)*4 + r (4 consecutive) -> vector stores, 64B lines.
  const int q4 = (lane >> 4) * 4;
  #pragma unroll
  for (int mi = 0; mi < 8; ++mi) {
    const int row = m0 + wm * 128 + mi * 16 + (lane & 15);
    #pragma unroll
    for (int ni = 0; ni < 4; ++ni) {
      const int ncol = n0 + wn * 64 + ni * 16 + q4;
      const f32x4 bv = *(const f32x4*)(bias + ncol);
      f32x4 v = acc[mi][ni];
      v.x += bv.x; v.y += bv.y; v.z += bv.z; v.w += bv.w;
      if constexpr (sizeof(OUT) == 2) {
        u32x2 pk;
        pk.x = ((unsigned)f32_to_bf16(v.y) << 16) | (unsigned)f32_to_bf16(v.x);
        pk.y = ((unsigned)f32_to_bf16(v.w) << 16) | (unsigned)f32_to_bf16(v.z);
        *(u32x2*)((unsigned short*)C + (size_t)row * N + ncol) = pk;
      } else {
        *(f32x4*)((float*)C + (size_t)row * N + ncol) = v;
      }
    }
  }
}

// ---------------- scan phase A: per-chunk local carry (bf16 u) ---------------
// R3-proven layout: 1024 blocks x 256 thr (16 waves/CU TLP); wave reads 64
// consecutive u-columns at each row j -> coalesced 128B/wave-instruction.
// Empirically beats 16B/lane variants with fewer waves (R5/R6 regressions)
// and the cooperative fusion (R8: hipLaunchCooperativeKernel not graph-
// capturable in this harness -> silent launch failure).
__global__ __launch_bounds__(256) void scan_carry(
    const unsigned short* __restrict__ u, const float* __restrict__ params_log,
    float* __restrict__ carry)
{
  int uu = blockIdx.x * 256 + threadIdx.x;
  int c  = blockIdx.y;
  int b  = blockIdx.z;
  float l = expf(-expf(params_log[uu]));
  const unsigned short* p = u + (size_t)(b * L_DIM + c * LC) * U_DIM + uu;
  float s = 0.f;
  #pragma unroll 8
  for (int j = 0; j < LC; ++j)
    s = fmaf(s, l, bf16_to_f32(p[(size_t)j * U_DIM]));
  carry[((size_t)b * NCH + c) * U_DIM + uu] = s;
}

// ---------------- scan phase B: prefix over chunk carries (wave-parallel) ----
// One wave per (b,u); lane c holds chunk-c carry; Hillis-Steele scan of the
// affine recurrence via (a,s) o (a',s') = (a*a', a*s'+s).
__global__ __launch_bounds__(256) void scan_prefix(
    const float* __restrict__ carry, const float* __restrict__ params_log,
    float* __restrict__ prefix)
{
  int wid  = (blockIdx.x * 256 + threadIdx.x) >> 6;   // wave id over B*U
  int lane = threadIdx.x & 63;
  int b  = wid >> 10;
  int uu = wid & (U_DIM - 1);
  float lp = expf(-expf(params_log[uu]) * (float)LC);
  const float* cp = carry + (size_t)b * NCH * U_DIM + uu;
  float s = cp[(size_t)lane * U_DIM];   // v_lane
  float a = lp;
  #pragma unroll
  for (int d = 1; d < 64; d <<= 1) {
    float s_up = __shfl_up(s, d, 64);
    float a_up = __shfl_up(a, d, 64);
    if (lane >= d) { s = fmaf(a, s_up, s); a *= a_up; }
  }
  float ex = __shfl_up(s, 1, 64);
  if (lane == 0) ex = 0.f;
  prefix[((size_t)b * NCH + lane) * U_DIM + uu] = ex;
}

// ---------------- scan phase C: local scan + carry-in, *gamma, bf16 out ------
// R3-proven layout: 1024 blocks x 256 thr, coalesced scalar stream.
__global__ __launch_bounds__(256) void scan_apply(
    const unsigned short* __restrict__ u, const float* __restrict__ params_log,
    const float* __restrict__ prefix, unsigned short* __restrict__ x_b)
{
  int uu = blockIdx.x * 256 + threadIdx.x;
  int c  = blockIdx.y;
  int b  = blockIdx.z;
  float l = expf(-expf(params_log[uu]));
  float g = expf(params_log[U_DIM + uu]);
  float s = prefix[((size_t)b * NCH + c) * U_DIM + uu];
  const unsigned short* p = u + (size_t)(b * L_DIM + c * LC) * U_DIM + uu;
  unsigned short* q = x_b + (size_t)(b * L_DIM + c * LC) * U_DIM + uu;
  #pragma unroll 8
  for (int j = 0; j < LC; ++j) {
    s = fmaf(s, l, bf16_to_f32(p[(size_t)j * U_DIM]));
    q[(size_t)j * U_DIM] = f32_to_bf16(s * g);
  }
}

extern "C" void kernel_launch(void* const* d_in, const int* in_sizes, int n_in,
                              void* d_out, int out_size, void* d_ws, size_t ws_size,
                              hipStream_t stream)
{
  const float* inputs     = (const float*)d_in[0];   // (B, L, H)
  const float* Wi         = (const float*)d_in[1];   // (U, H)
  const float* bi         = (const float*)d_in[2];   // (U,)
  const float* Wo         = (const float*)d_in[3];   // (H, U)
  const float* bo         = (const float*)d_in[4];   // (H,)
  const float* params_log = (const float*)d_in[5];   // (2, U)
  float* out = (float*)d_out;                        // (B, L, H) fp32

  char* ws = (char*)d_ws;
  unsigned short* u_b    = (unsigned short*)(ws);                 // 32 MB bf16 u
  unsigned short* x_b    = (unsigned short*)(ws + (32u << 20));   // 32 MB bf16 x
  unsigned short* in_b   = (unsigned short*)(ws + (64u << 20));   // 32 MB bf16 inputs
  unsigned short* wi_b   = (unsigned short*)(ws + (96u << 20));   //  2 MB bf16 Wi
  unsigned short* wo_b   = (unsigned short*)(ws + (98u << 20));   //  2 MB bf16 Wo
  float*          carry  = (float*)(ws + (100u << 20));           //  1 MB
  float*          prefix = (float*)(ws + (101u << 20));           //  1 MB

  cvt_all<<<dim3((CVT_TOTAL / 8 + 255) / 256), 256, 0, stream>>>(
      inputs, Wi, Wo, in_b, wi_b, wo_b);

  // GEMM1: u = inputs @ Wi^T + bi   (M=16384, N=U, K=H) -> bf16
  gemm256<unsigned short><<<dim3((M_DIM / BM) * (U_DIM / BN)), 512, 0, stream>>>(
      in_b, wi_b, bi, u_b, M_DIM, U_DIM, H_DIM);

  scan_carry <<<dim3(U_DIM / 256, NCH, B_DIM), 256, 0, stream>>>(u_b, params_log, carry);
  scan_prefix<<<dim3(B_DIM * U_DIM * 64 / 256), 256, 0, stream>>>(carry, params_log, prefix);
  scan_apply <<<dim3(U_DIM / 256, NCH, B_DIM), 256, 0, stream>>>(u_b, params_log, prefix, x_b);

  // GEMM2: out = x @ Wo^T + bo   (M=16384, N=H, K=U) -> fp32
  gemm256<float><<<dim3((M_DIM / BM) * (H_DIM / BN)), 512, 0, stream>>>(
      x_b, wo_b, bo, out, M_DIM, H_DIM, U_DIM);
}